// Round 4
// baseline (2368.347 us; speedup 1.0000x reference)
//
#include <hip/hip_runtime.h>
#include <hip/hip_bf16.h>

typedef _Float16 half8 __attribute__((ext_vector_type(8)));
typedef float floatx4 __attribute__((ext_vector_type(4)));
typedef float floatx2 __attribute__((ext_vector_type(2)));

#define N_NODES 10000
#define F_NODE  128
#define C_GCN   64
#define N_EDGES 160000
#define T_SEQ   96
#define S_SEQ   32
#define HID     128
#define M_BLK   40          // nodes per block (250 blocks exactly)
#define MT      3           // 3 m-tiles of 16 -> 48 rows (40 real + 8 zero pad)
#define SEQ_STRIDE 104      // 96 + 8 f16 pad (208 B, 16B multiple)
#define H_STRIDE   136      // 128 + 8 f16 pad (272 B, 16B multiple)

// ---------------- fast activations (f32, v_rcp based) ----------------
__device__ __forceinline__ float fast_rcp(float x) { return __builtin_amdgcn_rcpf(x); }
__device__ __forceinline__ float sigm_f(float x) {
    return fast_rcp(1.0f + exp2f(x * -1.44269504088896f));
}
__device__ __forceinline__ float tanh_f(float x) {
    return 1.0f - 2.0f * fast_rcp(1.0f + exp2f(x * 2.88539008177793f));
}

// ---------------- GCN kernels (all fp32, tiny) ----------------
__global__ void k_gcn_xw(const float* __restrict__ nf, const float* __restrict__ w,
                         float* __restrict__ xw) {
    int tid = blockIdx.x * 256 + threadIdx.x;
    int n = tid >> 6, c = tid & 63;
    if (n >= N_NODES) return;
    float s = 0.f;
    #pragma unroll 8
    for (int k = 0; k < F_NODE; ++k) s = fmaf(nf[n * F_NODE + k], w[k * C_GCN + c], s);
    xw[n * C_GCN + c] = s;
}

__global__ void k_deg_init(float* __restrict__ deg) {
    int i = blockIdx.x * 256 + threadIdx.x;
    if (i < N_NODES) deg[i] = 1.0f;   // self loop
}

__global__ void k_deg_count(const int* __restrict__ ei, float* __restrict__ deg) {
    int e = blockIdx.x * 256 + threadIdx.x;
    if (e < N_EDGES) atomicAdd(&deg[ei[N_EDGES + e]], 1.0f);
}

__global__ void k_dinv(const float* __restrict__ deg, float* __restrict__ dinv) {
    int i = blockIdx.x * 256 + threadIdx.x;
    if (i < N_NODES) dinv[i] = rsqrtf(deg[i]);
}

__global__ void k_gcn_self(const float* __restrict__ xw, const float* __restrict__ dinv,
                           const float* __restrict__ gb, float* __restrict__ gout) {
    int tid = blockIdx.x * 256 + threadIdx.x;
    int n = tid >> 6, c = tid & 63;
    if (n >= N_NODES) return;
    float di = dinv[n];
    gout[tid] = xw[tid] * di * di + gb[c];
}

__global__ void k_gcn_scatter(const int* __restrict__ ei, const float* __restrict__ xw,
                              const float* __restrict__ dinv, float* __restrict__ gout) {
    int e = blockIdx.x * 4 + (threadIdx.x >> 6);
    int c = threadIdx.x & 63;
    if (e >= N_EDGES) return;
    int r  = ei[e];
    int cl = ei[N_EDGES + e];
    float nm = dinv[r] * dinv[cl];
    atomicAdd(&gout[cl * C_GCN + c], xw[r * C_GCN + c] * nm);
}

// ---------------- weight packing: f32 [512][K] -> f16 MFMA-frag-linear ----------------
// frag id f = nt*KT + kt; per frag 64 lanes x 8 f16.
// lane holds B[k = kt*32 + (lane>>4)*8 + j][n = nt*16 + (lane&15)] = W[n][k]
__global__ void k_pack(const float* __restrict__ w_ih0, const float* __restrict__ w_hh0,
                       const float* __restrict__ w_ih1, const float* __restrict__ w_hh1,
                       half8* __restrict__ pW) {
    int tid = blockIdx.x * 256 + threadIdx.x;
    if (tid >= 480 * 64) return;
    int fid = tid >> 6, lane = tid & 63;
    const float* src; int KT, fbase;
    if (fid < 96)       { src = w_ih0; KT = 3; fbase = 0;   }
    else if (fid < 224) { src = w_hh0; KT = 4; fbase = 96;  }
    else if (fid < 352) { src = w_ih1; KT = 4; fbase = 224; }
    else                { src = w_hh1; KT = 4; fbase = 352; }
    int f  = fid - fbase;
    int nt = f / KT, kt = f % KT;
    int K  = KT * 32;
    int g  = nt * 16 + (lane & 15);
    int k0 = kt * 32 + (lane >> 4) * 8;
    half8 v;
    #pragma unroll
    for (int j = 0; j < 8; ++j) v[j] = (_Float16)src[g * K + k0 + j];
    pW[tid] = v;
}

__global__ void k_bsum(const float* __restrict__ bi0, const float* __restrict__ bh0,
                       const float* __restrict__ bi1, const float* __restrict__ bh1,
                       float* __restrict__ bs) {
    int i = blockIdx.x * 256 + threadIdx.x;
    if (i < 512)       bs[i] = bi0[i] + bh0[i];
    else if (i < 1024) bs[i] = bi1[i - 512] + bh1[i - 512];
}

// ---------------- fused 2-layer LSTM + FC ----------------
// issue a batch of 4*KT B-frag loads (no wait until first MFMA use)
template<int KT>
__device__ __forceinline__ void load_bfrags(half8* dst, const half8* __restrict__ pack,
                                            int wid, int lane) {
    #pragma unroll
    for (int g = 0; g < 4; ++g)
        #pragma unroll
        for (int kt = 0; kt < KT; ++kt)
            dst[g * KT + kt] = pack[(size_t)((8 * g + wid) * KT + kt) * 64 + lane];
}

// MFMA over one weight matrix with pre-loaded register B-frags
template<int KT>
__device__ __forceinline__ void gemm_pre(floatx4 acc[4][MT], const half8* bfr,
                                         const _Float16* A, int strideA, int l15, int quad) {
    #pragma unroll
    for (int kt = 0; kt < KT; ++kt) {
        half8 a[MT];
        #pragma unroll
        for (int mt = 0; mt < MT; ++mt)
            a[mt] = *(const half8*)(A + (mt * 16 + l15) * strideA + kt * 32 + quad * 8);
        #pragma unroll
        for (int g = 0; g < 4; ++g)
            #pragma unroll
            for (int mt = 0; mt < MT; ++mt)
                acc[g][mt] = __builtin_amdgcn_mfma_f32_16x16x32_f16(a[mt], bfr[g * KT + kt],
                                                                    acc[g][mt], 0, 0, 0);
    }
}

__device__ __forceinline__ void epilogue(floatx4 acc[4][MT],
                                         float c[MT][4], _Float16* Hnext,
                                         int quad, int ch) {
    #pragma unroll
    for (int mt = 0; mt < MT; ++mt) {
        #pragma unroll
        for (int r = 0; r < 4; ++r) {
            float gi = acc[0][mt][r];
            float gf = acc[1][mt][r];
            float gg = acc[2][mt][r];
            float go = acc[3][mt][r];
            float cn = sigm_f(gf) * c[mt][r] + sigm_f(gi) * tanh_f(gg);
            c[mt][r] = cn;
            float h = sigm_f(go) * tanh_f(cn);
            Hnext[(mt * 16 + quad * 4 + r) * H_STRIDE + ch] = (_Float16)h;
        }
    }
}

__global__ __launch_bounds__(512, 2) void k_lstm(
    const float* __restrict__ seq, const float* __restrict__ gcn,
    const half8* __restrict__ pW, const float* __restrict__ bsum,
    const float* __restrict__ fcw, const float* __restrict__ fcb,
    float* __restrict__ out) {

    __shared__ __align__(16) _Float16 sSeq[48 * SEQ_STRIDE];
    __shared__ __align__(16) _Float16 sH0[2][48 * H_STRIDE];
    __shared__ __align__(16) _Float16 sH1[2][48 * H_STRIDE];

    const int tid  = threadIdx.x;
    const int wid  = tid >> 6;
    const int lane = tid & 63;
    const int l15  = lane & 15;
    const int quad = lane >> 4;
    const int node0 = blockIdx.x * M_BLK;
    const int ch = wid * 16 + l15;      // this wave's hidden channel for epilogue

    const half8* pIH0 = pW;
    const half8* pHH0 = pW + 96  * 64;
    const half8* pIH1 = pW + 224 * 64;
    const half8* pHH1 = pW + 352 * 64;

    // phase-A weight batch for t=0: in flight during all the setup below
    half8 bA[28];
    load_bfrags<3>(bA, pIH0, wid, lane);
    load_bfrags<4>(bA + 12, pHH0, wid, lane);
    half8 bB[32];

    // zero LDS (pad rows 40..47 of A stay zero forever)
    for (int i = tid; i < 48 * SEQ_STRIDE; i += 512) sSeq[i] = (_Float16)0.f;
    for (int i = tid; i < 48 * H_STRIDE; i += 512) {
        sH0[0][i] = (_Float16)0.f; sH0[1][i] = (_Float16)0.f;
        sH1[0][i] = (_Float16)0.f; sH1[1][i] = (_Float16)0.f;
    }

    // biases (i,f,g,o for this lane's channel)
    float bias0[4], bias1[4];
    #pragma unroll
    for (int g = 0; g < 4; ++g) {
        bias0[g] = bsum[g * 128 + ch];
        bias1[g] = bsum[512 + g * 128 + ch];
    }

    float c0[MT][4] = {{0}}, c1[MT][4] = {{0}};

    __syncthreads();  // zeros visible before staging writes mix in

    // stage constant gcn columns (32..95) and seq t=0 (cols 0..31)
    for (int i = tid; i < M_BLK * (C_GCN / 2); i += 512) {
        int r = i >> 5, cp = (i & 31) * 2;
        floatx2 v = *(const floatx2*)(gcn + (size_t)(node0 + r) * C_GCN + cp);
        sSeq[r * SEQ_STRIDE + S_SEQ + cp]     = (_Float16)v.x;
        sSeq[r * SEQ_STRIDE + S_SEQ + cp + 1] = (_Float16)v.y;
    }
    {
        int r = tid >> 4, cp = (tid & 15) * 2;
        if (tid < M_BLK * 16) {
            floatx2 v = __builtin_nontemporal_load(
                (const floatx2*)(seq + ((size_t)(node0 + r) * T_SEQ) * S_SEQ + cp));
            sSeq[r * SEQ_STRIDE + cp]     = (_Float16)v.x;
            sSeq[r * SEQ_STRIDE + cp + 1] = (_Float16)v.y;
        }
    }
    __syncthreads();

    floatx4 acc[4][MT];
    const int pr = tid >> 4, pc = (tid & 15) * 2;   // seq prefetch slot

    for (int t = 0; t < T_SEQ; ++t) {
        const int cur = t & 1, nxt = cur ^ 1;

        // register prefetch of seq(t+1): non-temporal, in flight through phase A
        floatx2 pf0 = {0.f, 0.f}, pf1 = {0.f, 0.f};
        if (t + 1 < T_SEQ) {
            pf0 = __builtin_nontemporal_load(
                (const floatx2*)(seq + ((size_t)(node0 + pr) * T_SEQ + (t + 1)) * S_SEQ + pc));
            if (tid < 128) {
                int r1 = (512 + tid) >> 4, c1r = ((512 + tid) & 15) * 2;
                pf1 = __builtin_nontemporal_load(
                    (const floatx2*)(seq + ((size_t)(node0 + r1) * T_SEQ + (t + 1)) * S_SEQ + c1r));
            }
        }

        // ---- phase A: layer 0 ----
        #pragma unroll
        for (int g = 0; g < 4; ++g) {
            floatx4 bv = {bias0[g], bias0[g], bias0[g], bias0[g]};
            #pragma unroll
            for (int mt = 0; mt < MT; ++mt) acc[g][mt] = bv;
        }
        gemm_pre<3>(acc, bA, sSeq, SEQ_STRIDE, l15, quad);
        gemm_pre<4>(acc, bA + 12, &sH0[cur][0], H_STRIDE, l15, quad);
        // issue phase-B weight batch; hidden behind epilogue + barrier
        load_bfrags<4>(bB, pIH1, wid, lane);
        load_bfrags<4>(bB + 16, pHH1, wid, lane);
        epilogue(acc, c0, &sH0[nxt][0], quad, ch);
        __syncthreads();  // h0(t) visible for layer 1

        // ---- phase B: layer 1 ----
        #pragma unroll
        for (int g = 0; g < 4; ++g) {
            floatx4 bv = {bias1[g], bias1[g], bias1[g], bias1[g]};
            #pragma unroll
            for (int mt = 0; mt < MT; ++mt) acc[g][mt] = bv;
        }
        gemm_pre<4>(acc, bB, &sH0[nxt][0], H_STRIDE, l15, quad);
        gemm_pre<4>(acc, bB + 16, &sH1[cur][0], H_STRIDE, l15, quad);
        // issue phase-A weight batch for t+1; hidden behind epilogue + barrier
        load_bfrags<3>(bA, pIH0, wid, lane);
        load_bfrags<4>(bA + 12, pHH0, wid, lane);
        // commit seq(t+1) from prefetch regs (phase-A readers of sSeq are done)
        if (t + 1 < T_SEQ) {
            sSeq[pr * SEQ_STRIDE + pc]     = (_Float16)pf0.x;
            sSeq[pr * SEQ_STRIDE + pc + 1] = (_Float16)pf0.y;
            if (tid < 128) {
                int r1 = (512 + tid) >> 4, c1r = ((512 + tid) & 15) * 2;
                sSeq[r1 * SEQ_STRIDE + c1r]     = (_Float16)pf1.x;
                sSeq[r1 * SEQ_STRIDE + c1r + 1] = (_Float16)pf1.y;
            }
        }
        epilogue(acc, c1, &sH1[nxt][0], quad, ch);
        __syncthreads();  // h1(t) + seq(t+1) visible
    }

    // final h1 lives in buffer (T_SEQ & 1) == 0
    if (tid < M_BLK) {
        const _Float16* h1 = &sH1[0][tid * H_STRIDE];
        float s = fcb[0];
        #pragma unroll 16
        for (int k = 0; k < HID; ++k) s = fmaf((float)h1[k], fcw[k], s);
        out[node0 + tid] = s;
    }
}

// ---------------- launch ----------------
extern "C" void kernel_launch(void* const* d_in, const int* in_sizes, int n_in,
                              void* d_out, int out_size, void* d_ws, size_t ws_size,
                              hipStream_t stream) {
    const float* seq   = (const float*)d_in[0];
    const int*   ei    = (const int*)d_in[1];     // int64 in reference -> int32 on device
    // d_in[2] edge_attr: unused by reference
    const float* nf    = (const float*)d_in[3];
    // d_in[4] node_indices: unused by reference
    const float* gcn_w = (const float*)d_in[5];
    const float* gcn_b = (const float*)d_in[6];
    const float* w_ih0 = (const float*)d_in[7];
    const float* w_hh0 = (const float*)d_in[8];
    const float* b_ih0 = (const float*)d_in[9];
    const float* b_hh0 = (const float*)d_in[10];
    const float* w_ih1 = (const float*)d_in[11];
    const float* w_hh1 = (const float*)d_in[12];
    const float* b_ih1 = (const float*)d_in[13];
    const float* b_hh1 = (const float*)d_in[14];
    const float* fc_w  = (const float*)d_in[15];
    const float* fc_b  = (const float*)d_in[16];
    float* out = (float*)d_out;

    char* ws = (char*)d_ws;
    float* xw   = (float*)(ws);                    // 2,560,000 B
    float* gout = (float*)(ws + 2621440);          // 2,560,000 B
    float* deg  = (float*)(ws + 5242880);          // 40,000 B
    float* dinv = (float*)(ws + 5283840);          // 40,000 B
    float* bsum = (float*)(ws + 5324800);          // 4,096 B
    half8* pW   = (half8*)(ws + 5328896);          // 491,520 B  (16B aligned)

    // GCN (fp32 exact)
    k_gcn_xw     <<<2500,  256, 0, stream>>>(nf, gcn_w, xw);
    k_deg_init   <<<40,    256, 0, stream>>>(deg);
    k_deg_count  <<<625,   256, 0, stream>>>(ei, deg);
    k_dinv       <<<40,    256, 0, stream>>>(deg, dinv);
    k_gcn_self   <<<2500,  256, 0, stream>>>(xw, dinv, gcn_b, gout);
    k_gcn_scatter<<<40000, 256, 0, stream>>>(ei, xw, dinv, gout);

    // weight prep
    k_pack<<<120, 256, 0, stream>>>(w_ih0, w_hh0, w_ih1, w_hh1, pW);
    k_bsum<<<4,   256, 0, stream>>>(b_ih0, b_hh0, b_ih1, b_hh1, bsum);

    // fused 2-layer LSTM + FC
    k_lstm<<<250, 512, 0, stream>>>(seq, gout, pW, bsum, fc_w, fc_b, out);
}

// Round 5
// 2037.021 us; speedup vs baseline: 1.1627x; 1.1627x over previous
//
#include <hip/hip_runtime.h>
#include <hip/hip_bf16.h>

typedef _Float16 half8 __attribute__((ext_vector_type(8)));
typedef float floatx4 __attribute__((ext_vector_type(4)));
typedef float floatx2 __attribute__((ext_vector_type(2)));

#define N_NODES 10000
#define F_NODE  128
#define C_GCN   64
#define N_EDGES 160000
#define T_SEQ   96
#define S_SEQ   32
#define HID     128
#define M_BLK   40          // nodes per block (250 blocks exactly)
#define MT      3           // 3 m-tiles of 16 -> 48 rows (40 real + 8 zero pad)
#define SEQ_STRIDE 104      // 96 + 8 f16 pad (208 B, 16B multiple)
#define H_STRIDE   136      // 128 + 8 f16 pad (272 B, 16B multiple)

// ---------------- fast activations (f32, v_rcp based) ----------------
__device__ __forceinline__ float fast_rcp(float x) { return __builtin_amdgcn_rcpf(x); }
__device__ __forceinline__ float sigm_f(float x) {
    return fast_rcp(1.0f + exp2f(x * -1.44269504088896f));
}
__device__ __forceinline__ float tanh_f(float x) {
    return 1.0f - 2.0f * fast_rcp(1.0f + exp2f(x * 2.88539008177793f));
}

// ---------------- GCN kernels (all fp32, tiny) ----------------
__global__ void k_gcn_xw(const float* __restrict__ nf, const float* __restrict__ w,
                         float* __restrict__ xw) {
    int tid = blockIdx.x * 256 + threadIdx.x;
    int n = tid >> 6, c = tid & 63;
    if (n >= N_NODES) return;
    float s = 0.f;
    #pragma unroll 8
    for (int k = 0; k < F_NODE; ++k) s = fmaf(nf[n * F_NODE + k], w[k * C_GCN + c], s);
    xw[n * C_GCN + c] = s;
}

__global__ void k_deg_init(float* __restrict__ deg) {
    int i = blockIdx.x * 256 + threadIdx.x;
    if (i < N_NODES) deg[i] = 1.0f;   // self loop
}

__global__ void k_deg_count(const int* __restrict__ ei, float* __restrict__ deg) {
    int e = blockIdx.x * 256 + threadIdx.x;
    if (e < N_EDGES) atomicAdd(&deg[ei[N_EDGES + e]], 1.0f);
}

__global__ void k_dinv(const float* __restrict__ deg, float* __restrict__ dinv) {
    int i = blockIdx.x * 256 + threadIdx.x;
    if (i < N_NODES) dinv[i] = rsqrtf(deg[i]);
}

__global__ void k_gcn_self(const float* __restrict__ xw, const float* __restrict__ dinv,
                           const float* __restrict__ gb, float* __restrict__ gout) {
    int tid = blockIdx.x * 256 + threadIdx.x;
    int n = tid >> 6, c = tid & 63;
    if (n >= N_NODES) return;
    float di = dinv[n];
    gout[tid] = xw[tid] * di * di + gb[c];
}

__global__ void k_gcn_scatter(const int* __restrict__ ei, const float* __restrict__ xw,
                              const float* __restrict__ dinv, float* __restrict__ gout) {
    int e = blockIdx.x * 4 + (threadIdx.x >> 6);
    int c = threadIdx.x & 63;
    if (e >= N_EDGES) return;
    int r  = ei[e];
    int cl = ei[N_EDGES + e];
    float nm = dinv[r] * dinv[cl];
    atomicAdd(&gout[cl * C_GCN + c], xw[r * C_GCN + c] * nm);
}

// ---------------- weight packing: f32 [512][K] -> f16 MFMA-frag-linear ----------------
// frag id f = nt*KT + kt; per frag 64 lanes x 8 f16.
// lane holds B[k = kt*32 + (lane>>4)*8 + j][n = nt*16 + (lane&15)] = W[n][k]
__global__ void k_pack(const float* __restrict__ w_ih0, const float* __restrict__ w_hh0,
                       const float* __restrict__ w_ih1, const float* __restrict__ w_hh1,
                       half8* __restrict__ pW) {
    int tid = blockIdx.x * 256 + threadIdx.x;
    if (tid >= 480 * 64) return;
    int fid = tid >> 6, lane = tid & 63;
    const float* src; int KT, fbase;
    if (fid < 96)       { src = w_ih0; KT = 3; fbase = 0;   }
    else if (fid < 224) { src = w_hh0; KT = 4; fbase = 96;  }
    else if (fid < 352) { src = w_ih1; KT = 4; fbase = 224; }
    else                { src = w_hh1; KT = 4; fbase = 352; }
    int f  = fid - fbase;
    int nt = f / KT, kt = f % KT;
    int K  = KT * 32;
    int g  = nt * 16 + (lane & 15);
    int k0 = kt * 32 + (lane >> 4) * 8;
    half8 v;
    #pragma unroll
    for (int j = 0; j < 8; ++j) v[j] = (_Float16)src[g * K + k0 + j];
    pW[tid] = v;
}

__global__ void k_bsum(const float* __restrict__ bi0, const float* __restrict__ bh0,
                       const float* __restrict__ bi1, const float* __restrict__ bh1,
                       float* __restrict__ bs) {
    int i = blockIdx.x * 256 + threadIdx.x;
    if (i < 512)       bs[i] = bi0[i] + bh0[i];
    else if (i < 1024) bs[i] = bi1[i - 512] + bh1[i - 512];
}

// ---------------- fused 2-layer LSTM + FC ----------------
// load one k-tile "slot": 4 gates' B-frags (16 VGPRs)
__device__ __forceinline__ void load_slot(half8 bg[4], const half8* __restrict__ p,
                                          int KT, int kt, int wid, int lane) {
    #pragma unroll
    for (int g = 0; g < 4; ++g)
        bg[g] = p[(size_t)(((8 * g + wid) * KT + kt) * 64 + lane)];
}

// one k-tile of MFMA: 3 ds_read_b128 (A) + 12 MFMAs against the slot's 4 gate-frags
__device__ __forceinline__ void mfma_kt(floatx4 acc[4][MT], const half8 bg[4],
                                        const _Float16* A, int strideA, int koff,
                                        int l15, int quad) {
    half8 a[MT];
    #pragma unroll
    for (int mt = 0; mt < MT; ++mt)
        a[mt] = *(const half8*)(A + (mt * 16 + l15) * strideA + koff + quad * 8);
    #pragma unroll
    for (int g = 0; g < 4; ++g)
        #pragma unroll
        for (int mt = 0; mt < MT; ++mt)
            acc[g][mt] = __builtin_amdgcn_mfma_f32_16x16x32_f16(a[mt], bg[g], acc[g][mt], 0, 0, 0);
}

__device__ __forceinline__ void epilogue(floatx4 acc[4][MT],
                                         float c[MT][4], _Float16* Hnext,
                                         int quad, int ch) {
    #pragma unroll
    for (int mt = 0; mt < MT; ++mt) {
        #pragma unroll
        for (int r = 0; r < 4; ++r) {
            float gi = acc[0][mt][r];
            float gf = acc[1][mt][r];
            float gg = acc[2][mt][r];
            float go = acc[3][mt][r];
            float cn = sigm_f(gf) * c[mt][r] + sigm_f(gi) * tanh_f(gg);
            c[mt][r] = cn;
            float h = sigm_f(go) * tanh_f(cn);
            Hnext[(mt * 16 + quad * 4 + r) * H_STRIDE + ch] = (_Float16)h;
        }
    }
}

__global__ __launch_bounds__(512, 2) void k_lstm(
    const float* __restrict__ seq, const float* __restrict__ gcn,
    const half8* __restrict__ pW, const float* __restrict__ bsum,
    const float* __restrict__ fcw, const float* __restrict__ fcb,
    float* __restrict__ out) {

    __shared__ __align__(16) _Float16 sSeq[48 * SEQ_STRIDE];
    __shared__ __align__(16) _Float16 sH0[2][48 * H_STRIDE];
    __shared__ __align__(16) _Float16 sH1[2][48 * H_STRIDE];

    const int tid  = threadIdx.x;
    const int wid  = tid >> 6;
    const int lane = tid & 63;
    const int l15  = lane & 15;
    const int quad = lane >> 4;
    const int node0 = blockIdx.x * M_BLK;
    const int ch = wid * 16 + l15;      // this wave's hidden channel for epilogue

    const half8* pIH0 = pW;
    const half8* pHH0 = pW + 96  * 64;
    const half8* pIH1 = pW + 224 * 64;
    const half8* pHH1 = pW + 352 * 64;

    // ring buffers: 4 slots x 4 gate-frags (16 VGPRs per slot)
    half8 bA[4][4], bB[4][4];

    // prologue: phase-A slots kt=0..2 (pIH0) in flight during LDS zero/stage
    #pragma unroll
    for (int kt = 0; kt < 3; ++kt) load_slot(bA[kt], pIH0, 3, kt, wid, lane);

    // zero LDS (pad rows 40..47 of A stay zero in sSeq forever)
    for (int i = tid; i < 48 * SEQ_STRIDE; i += 512) sSeq[i] = (_Float16)0.f;
    for (int i = tid; i < 48 * H_STRIDE; i += 512) {
        sH0[0][i] = (_Float16)0.f; sH0[1][i] = (_Float16)0.f;
        sH1[0][i] = (_Float16)0.f; sH1[1][i] = (_Float16)0.f;
    }

    // biases (i,f,g,o for this lane's channel)
    float bias0[4], bias1[4];
    #pragma unroll
    for (int g = 0; g < 4; ++g) {
        bias0[g] = bsum[g * 128 + ch];
        bias1[g] = bsum[512 + g * 128 + ch];
    }

    float c0[MT][4] = {{0}}, c1[MT][4] = {{0}};

    __syncthreads();  // zeros visible before staging writes mix in

    // stage constant gcn columns (32..95) and seq t=0 (cols 0..31)
    for (int i = tid; i < M_BLK * (C_GCN / 2); i += 512) {
        int r = i >> 5, cp = (i & 31) * 2;
        floatx2 v = *(const floatx2*)(gcn + (size_t)(node0 + r) * C_GCN + cp);
        sSeq[r * SEQ_STRIDE + S_SEQ + cp]     = (_Float16)v.x;
        sSeq[r * SEQ_STRIDE + S_SEQ + cp + 1] = (_Float16)v.y;
    }
    {
        int r = tid >> 4, cp = (tid & 15) * 2;
        if (tid < M_BLK * 16) {
            floatx2 v = *(const floatx2*)(seq + ((size_t)(node0 + r) * T_SEQ) * S_SEQ + cp);
            sSeq[r * SEQ_STRIDE + cp]     = (_Float16)v.x;
            sSeq[r * SEQ_STRIDE + cp + 1] = (_Float16)v.y;
        }
    }
    __syncthreads();

    floatx4 acc[4][MT];
    const int pr = tid >> 4, pc = (tid & 15) * 2;   // seq prefetch slot

    for (int t = 0; t < T_SEQ; ++t) {
        const int cur = t & 1, nxt = cur ^ 1;

        // register prefetch of seq(t+1): in flight through phase A
        floatx2 pf0 = {0.f, 0.f}, pf1 = {0.f, 0.f};
        if (t + 1 < T_SEQ) {
            pf0 = *(const floatx2*)(seq + ((size_t)(node0 + pr) * T_SEQ + (t + 1)) * S_SEQ + pc);
            if (tid < 128) {
                int r1 = (512 + tid) >> 4, c1r = ((512 + tid) & 15) * 2;
                pf1 = *(const floatx2*)(seq + ((size_t)(node0 + r1) * T_SEQ + (t + 1)) * S_SEQ + c1r);
            }
        }

        // ---- phase A: layer 0 (KT=7: kt 0..2 from sSeq/pIH0, kt 3..6 from sH0/pHH0) ----
        #pragma unroll
        for (int g = 0; g < 4; ++g) {
            floatx4 bv = {bias0[g], bias0[g], bias0[g], bias0[g]};
            #pragma unroll
            for (int mt = 0; mt < MT; ++mt) acc[g][mt] = bv;
        }
        #pragma unroll
        for (int kt = 0; kt < 7; ++kt) {
            if (kt + 3 < 7)   // prefetch slot kt+3 (always from pHH0: kt+3 in 3..6)
                load_slot(bA[(kt + 3) & 3], pHH0, 4, kt, wid, lane);
            if (kt < 3)
                mfma_kt(acc, bA[kt & 3], sSeq, SEQ_STRIDE, kt * 32, l15, quad);
            else
                mfma_kt(acc, bA[kt & 3], &sH0[cur][0], H_STRIDE, (kt - 3) * 32, l15, quad);
        }
        // pre-issue phase-B slots kt=0..2 (pIH1): hidden behind epilogue + barrier
        #pragma unroll
        for (int kt = 0; kt < 3; ++kt) load_slot(bB[kt], pIH1, 4, kt, wid, lane);
        epilogue(acc, c0, &sH0[nxt][0], quad, ch);
        __syncthreads();  // h0(t) visible for layer 1

        // ---- phase B: layer 1 (KT=8: kt 0..3 from sH0[nxt]/pIH1, kt 4..7 from sH1/pHH1) ----
        #pragma unroll
        for (int g = 0; g < 4; ++g) {
            floatx4 bv = {bias1[g], bias1[g], bias1[g], bias1[g]};
            #pragma unroll
            for (int mt = 0; mt < MT; ++mt) acc[g][mt] = bv;
        }
        #pragma unroll
        for (int kt = 0; kt < 8; ++kt) {
            if (kt + 3 < 8) {
                if (kt + 3 < 4) load_slot(bB[(kt + 3) & 3], pIH1, 4, kt + 3, wid, lane);
                else            load_slot(bB[(kt + 3) & 3], pHH1, 4, kt - 1, wid, lane);
            }
            if (kt < 4)
                mfma_kt(acc, bB[kt & 3], &sH0[nxt][0], H_STRIDE, kt * 32, l15, quad);
            else
                mfma_kt(acc, bB[kt & 3], &sH1[cur][0], H_STRIDE, (kt - 4) * 32, l15, quad);
        }
        // pre-issue next-t phase-A slots kt=0..2 (pIH0): hidden behind epilogue + barrier
        #pragma unroll
        for (int kt = 0; kt < 3; ++kt) load_slot(bA[kt], pIH0, 3, kt, wid, lane);
        // commit seq(t+1) from prefetch regs (phase-A readers of sSeq are done)
        if (t + 1 < T_SEQ) {
            sSeq[pr * SEQ_STRIDE + pc]     = (_Float16)pf0.x;
            sSeq[pr * SEQ_STRIDE + pc + 1] = (_Float16)pf0.y;
            if (tid < 128) {
                int r1 = (512 + tid) >> 4, c1r = ((512 + tid) & 15) * 2;
                sSeq[r1 * SEQ_STRIDE + c1r]     = (_Float16)pf1.x;
                sSeq[r1 * SEQ_STRIDE + c1r + 1] = (_Float16)pf1.y;
            }
        }
        epilogue(acc, c1, &sH1[nxt][0], quad, ch);
        __syncthreads();  // h1(t) + seq(t+1) visible
    }

    // final h1 lives in buffer (T_SEQ & 1) == 0
    if (tid < M_BLK) {
        const _Float16* h1 = &sH1[0][tid * H_STRIDE];
        float s = fcb[0];
        #pragma unroll 16
        for (int k = 0; k < HID; ++k) s = fmaf((float)h1[k], fcw[k], s);
        out[node0 + tid] = s;
    }
}

// ---------------- launch ----------------
extern "C" void kernel_launch(void* const* d_in, const int* in_sizes, int n_in,
                              void* d_out, int out_size, void* d_ws, size_t ws_size,
                              hipStream_t stream) {
    const float* seq   = (const float*)d_in[0];
    const int*   ei    = (const int*)d_in[1];     // int64 in reference -> int32 on device
    // d_in[2] edge_attr: unused by reference
    const float* nf    = (const float*)d_in[3];
    // d_in[4] node_indices: unused by reference
    const float* gcn_w = (const float*)d_in[5];
    const float* gcn_b = (const float*)d_in[6];
    const float* w_ih0 = (const float*)d_in[7];
    const float* w_hh0 = (const float*)d_in[8];
    const float* b_ih0 = (const float*)d_in[9];
    const float* b_hh0 = (const float*)d_in[10];
    const float* w_ih1 = (const float*)d_in[11];
    const float* w_hh1 = (const float*)d_in[12];
    const float* b_ih1 = (const float*)d_in[13];
    const float* b_hh1 = (const float*)d_in[14];
    const float* fc_w  = (const float*)d_in[15];
    const float* fc_b  = (const float*)d_in[16];
    float* out = (float*)d_out;

    char* ws = (char*)d_ws;
    float* xw   = (float*)(ws);                    // 2,560,000 B
    float* gout = (float*)(ws + 2621440);          // 2,560,000 B
    float* deg  = (float*)(ws + 5242880);          // 40,000 B
    float* dinv = (float*)(ws + 5283840);          // 40,000 B
    float* bsum = (float*)(ws + 5324800);          // 4,096 B
    half8* pW   = (half8*)(ws + 5328896);          // 491,520 B  (16B aligned)

    // GCN (fp32 exact)
    k_gcn_xw     <<<2500,  256, 0, stream>>>(nf, gcn_w, xw);
    k_deg_init   <<<40,    256, 0, stream>>>(deg);
    k_deg_count  <<<625,   256, 0, stream>>>(ei, deg);
    k_dinv       <<<40,    256, 0, stream>>>(deg, dinv);
    k_gcn_self   <<<2500,  256, 0, stream>>>(xw, dinv, gcn_b, gout);
    k_gcn_scatter<<<40000, 256, 0, stream>>>(ei, xw, dinv, gout);

    // weight prep
    k_pack<<<120, 256, 0, stream>>>(w_ih0, w_hh0, w_ih1, w_hh1, pW);
    k_bsum<<<4,   256, 0, stream>>>(b_ih0, b_hh0, b_ih1, b_hh1, bsum);

    // fused 2-layer LSTM + FC
    k_lstm<<<250, 512, 0, stream>>>(seq, gout, pW, bsum, fc_w, fc_b, out);
}

// Round 6
// 1523.939 us; speedup vs baseline: 1.5541x; 1.3367x over previous
//
#include <hip/hip_runtime.h>
#include <hip/hip_bf16.h>

typedef _Float16 half8 __attribute__((ext_vector_type(8)));
typedef float floatx4 __attribute__((ext_vector_type(4)));
typedef float floatx2 __attribute__((ext_vector_type(2)));

#define N_NODES 10000
#define F_NODE  128
#define C_GCN   64
#define N_EDGES 160000
#define T_SEQ   96
#define S_SEQ   32
#define HID     128
#define M_BLK   40          // nodes per block (250 blocks exactly)
#define MT      3           // 3 m-tiles of 16 -> 48 rows (40 real + 8 zero pad)
#define SEQ_STRIDE 104      // 96 + 8 f16 pad (208 B = 13*16, conflict-free for b128)
#define H_STRIDE   136      // 128 + 8 f16 pad (272 B = 17*16, conflict-free for b128)

// ---------------- fast activations (f32, v_rcp based) ----------------
__device__ __forceinline__ float fast_rcp(float x) { return __builtin_amdgcn_rcpf(x); }
__device__ __forceinline__ float sigm_f(float x) {
    return fast_rcp(1.0f + exp2f(x * -1.44269504088896f));
}
__device__ __forceinline__ float tanh_f(float x) {
    return 1.0f - 2.0f * fast_rcp(1.0f + exp2f(x * 2.88539008177793f));
}

// ---------------- GCN kernels (all fp32, tiny) ----------------
__global__ void k_gcn_xw(const float* __restrict__ nf, const float* __restrict__ w,
                         float* __restrict__ xw) {
    int tid = blockIdx.x * 256 + threadIdx.x;
    int n = tid >> 6, c = tid & 63;
    if (n >= N_NODES) return;
    float s = 0.f;
    #pragma unroll 8
    for (int k = 0; k < F_NODE; ++k) s = fmaf(nf[n * F_NODE + k], w[k * C_GCN + c], s);
    xw[n * C_GCN + c] = s;
}

__global__ void k_deg_init(float* __restrict__ deg) {
    int i = blockIdx.x * 256 + threadIdx.x;
    if (i < N_NODES) deg[i] = 1.0f;   // self loop
}

__global__ void k_deg_count(const int* __restrict__ ei, float* __restrict__ deg) {
    int e = blockIdx.x * 256 + threadIdx.x;
    if (e < N_EDGES) atomicAdd(&deg[ei[N_EDGES + e]], 1.0f);
}

__global__ void k_dinv(const float* __restrict__ deg, float* __restrict__ dinv) {
    int i = blockIdx.x * 256 + threadIdx.x;
    if (i < N_NODES) dinv[i] = rsqrtf(deg[i]);
}

__global__ void k_gcn_self(const float* __restrict__ xw, const float* __restrict__ dinv,
                           const float* __restrict__ gb, float* __restrict__ gout) {
    int tid = blockIdx.x * 256 + threadIdx.x;
    int n = tid >> 6, c = tid & 63;
    if (n >= N_NODES) return;
    float di = dinv[n];
    gout[tid] = xw[tid] * di * di + gb[c];
}

__global__ void k_gcn_scatter(const int* __restrict__ ei, const float* __restrict__ xw,
                              const float* __restrict__ dinv, float* __restrict__ gout) {
    int e = blockIdx.x * 4 + (threadIdx.x >> 6);
    int c = threadIdx.x & 63;
    if (e >= N_EDGES) return;
    int r  = ei[e];
    int cl = ei[N_EDGES + e];
    float nm = dinv[r] * dinv[cl];
    atomicAdd(&gout[cl * C_GCN + c], xw[r * C_GCN + c] * nm);
}

// ---------------- weight packing: f32 [512][K] -> f16 MFMA-frag-linear ----------------
// frag id f = nt*KT + kt; per frag 64 lanes x 8 f16 (1 KB, lane-contiguous).
// lane holds B[k = kt*32 + (lane>>4)*8 + j][n = nt*16 + (lane&15)] = W[n][k]
__global__ void k_pack(const float* __restrict__ w_ih0, const float* __restrict__ w_hh0,
                       const float* __restrict__ w_ih1, const float* __restrict__ w_hh1,
                       half8* __restrict__ pW) {
    int tid = blockIdx.x * 256 + threadIdx.x;
    if (tid >= 480 * 64) return;
    int fid = tid >> 6, lane = tid & 63;
    const float* src; int KT, fbase;
    if (fid < 96)       { src = w_ih0; KT = 3; fbase = 0;   }
    else if (fid < 224) { src = w_hh0; KT = 4; fbase = 96;  }
    else if (fid < 352) { src = w_ih1; KT = 4; fbase = 224; }
    else                { src = w_hh1; KT = 4; fbase = 352; }
    int f  = fid - fbase;
    int nt = f / KT, kt = f % KT;
    int K  = KT * 32;
    int g  = nt * 16 + (lane & 15);
    int k0 = kt * 32 + (lane >> 4) * 8;
    half8 v;
    #pragma unroll
    for (int j = 0; j < 8; ++j) v[j] = (_Float16)src[g * K + k0 + j];
    pW[tid] = v;
}

__global__ void k_bsum(const float* __restrict__ bi0, const float* __restrict__ bh0,
                       const float* __restrict__ bi1, const float* __restrict__ bh1,
                       float* __restrict__ bs) {
    int i = blockIdx.x * 256 + threadIdx.x;
    if (i < 512)       bs[i] = bi0[i] + bh0[i];
    else if (i < 1024) bs[i] = bi1[i - 512] + bh1[i - 512];
}

// ---------------- fused 2-layer LSTM + FC ----------------
// async 16B-per-lane DMA: global -> LDS (bypasses VGPRs; lds dest = uniform base + lane*16)
__device__ __forceinline__ void async_copy16(const void* g, void* l) {
    __builtin_amdgcn_global_load_lds(
        (const __attribute__((address_space(1))) unsigned int*)g,
        (__attribute__((address_space(3))) unsigned int*)l, 16, 0, 0);
}

// DMA one k-tile slot for this wave: 4 gate-frags x 1 KB into wave-private LDS slot
__device__ __forceinline__ void dma_slot(const half8* __restrict__ p, int KT, int kt,
                                         int wid, int lane, _Float16* slot) {
    #pragma unroll
    for (int g = 0; g < 4; ++g)
        async_copy16((const void*)(p + (size_t)(((8 * g + wid) * KT + kt) * 64 + lane)),
                     (void*)(slot + g * 512));
}

// consume one k-tile slot: 4 B ds_reads + 3 A ds_reads + 12 MFMAs
__device__ __forceinline__ void mfma_kt(floatx4 acc[4][MT], const _Float16* slot, int lane,
                                        const _Float16* A, int strideA, int koff,
                                        int l15, int quad) {
    half8 bg[4], a[MT];
    #pragma unroll
    for (int g = 0; g < 4; ++g) bg[g] = *(const half8*)(slot + g * 512 + lane * 8);
    #pragma unroll
    for (int mt = 0; mt < MT; ++mt)
        a[mt] = *(const half8*)(A + (mt * 16 + l15) * strideA + koff + quad * 8);
    #pragma unroll
    for (int g = 0; g < 4; ++g)
        #pragma unroll
        for (int mt = 0; mt < MT; ++mt)
            acc[g][mt] = __builtin_amdgcn_mfma_f32_16x16x32_f16(a[mt], bg[g], acc[g][mt], 0, 0, 0);
}

__device__ __forceinline__ void epilogue(floatx4 acc[4][MT],
                                         float c[MT][4], _Float16* Hnext,
                                         int quad, int ch) {
    #pragma unroll
    for (int mt = 0; mt < MT; ++mt) {
        #pragma unroll
        for (int r = 0; r < 4; ++r) {
            float gi = acc[0][mt][r];
            float gf = acc[1][mt][r];
            float gg = acc[2][mt][r];
            float go = acc[3][mt][r];
            float cn = sigm_f(gf) * c[mt][r] + sigm_f(gi) * tanh_f(gg);
            c[mt][r] = cn;
            float h = sigm_f(go) * tanh_f(cn);
            Hnext[(mt * 16 + quad * 4 + r) * H_STRIDE + ch] = (_Float16)h;
        }
    }
}

__global__ __launch_bounds__(512, 2) void k_lstm(
    const float* __restrict__ seq, const float* __restrict__ gcn,
    const half8* __restrict__ pW, const float* __restrict__ bsum,
    const float* __restrict__ fcw, const float* __restrict__ fcb,
    float* __restrict__ out) {

    __shared__ __align__(16) _Float16 sSeq[48 * SEQ_STRIDE];          //  9.75 KB
    __shared__ __align__(16) _Float16 sH0[2][48 * H_STRIDE];          // 25.5 KB
    __shared__ __align__(16) _Float16 sH1[2][48 * H_STRIDE];          // 25.5 KB
    __shared__ __align__(16) _Float16 sW[2][8][2048];                 // 64 KB weight ring

    const int tid  = threadIdx.x;
    const int wid  = tid >> 6;
    const int lane = tid & 63;
    const int l15  = lane & 15;
    const int quad = lane >> 4;
    const int node0 = blockIdx.x * M_BLK;
    const int ch = wid * 16 + l15;      // this wave's hidden channel for epilogue

    const half8* pIH0 = pW;
    const half8* pHH0 = pW + 96  * 64;
    const half8* pIH1 = pW + 224 * 64;
    const half8* pHH1 = pW + 352 * 64;

    // prologue DMA: phase-A kt0 weights into slot 0 (in flight during setup)
    dma_slot(pIH0, 3, 0, wid, lane, &sW[0][wid][0]);

    // zero LDS (pad rows 40..47 of A stay zero forever)
    for (int i = tid; i < 48 * SEQ_STRIDE; i += 512) sSeq[i] = (_Float16)0.f;
    for (int i = tid; i < 48 * H_STRIDE; i += 512) {
        sH0[0][i] = (_Float16)0.f; sH0[1][i] = (_Float16)0.f;
        sH1[0][i] = (_Float16)0.f; sH1[1][i] = (_Float16)0.f;
    }

    // biases (i,f,g,o for this lane's channel)
    float bias0[4], bias1[4];
    #pragma unroll
    for (int g = 0; g < 4; ++g) {
        bias0[g] = bsum[g * 128 + ch];
        bias1[g] = bsum[512 + g * 128 + ch];
    }

    float c0[MT][4] = {{0}}, c1[MT][4] = {{0}};

    __syncthreads();  // zeros visible before staging writes mix in

    // stage constant gcn columns (32..95) and seq t=0 (cols 0..31)
    for (int i = tid; i < M_BLK * (C_GCN / 2); i += 512) {
        int r = i >> 5, cp = (i & 31) * 2;
        floatx2 v = *(const floatx2*)(gcn + (size_t)(node0 + r) * C_GCN + cp);
        sSeq[r * SEQ_STRIDE + S_SEQ + cp]     = (_Float16)v.x;
        sSeq[r * SEQ_STRIDE + S_SEQ + cp + 1] = (_Float16)v.y;
    }
    {
        int r = tid >> 4, cp = (tid & 15) * 2;
        if (tid < M_BLK * 16) {
            floatx2 v = *(const floatx2*)(seq + ((size_t)(node0 + r) * T_SEQ) * S_SEQ + cp);
            sSeq[r * SEQ_STRIDE + cp]     = (_Float16)v.x;
            sSeq[r * SEQ_STRIDE + cp + 1] = (_Float16)v.y;
        }
    }
    __syncthreads();

    floatx4 acc[4][MT];
    const int pr = tid >> 4, pc = (tid & 15) * 2;   // seq prefetch slot
    int wb = 0;                                     // wave-private slot parity

    for (int t = 0; t < T_SEQ; ++t) {
        const int cur = t & 1, nxt = cur ^ 1;

        // register prefetch of seq(t+1): in flight through phase A
        floatx2 pf0 = {0.f, 0.f}, pf1 = {0.f, 0.f};
        if (t + 1 < T_SEQ) {
            pf0 = *(const floatx2*)(seq + ((size_t)(node0 + pr) * T_SEQ + (t + 1)) * S_SEQ + pc);
            if (tid < 128) {
                int r1 = (512 + tid) >> 4, c1r = ((512 + tid) & 15) * 2;
                pf1 = *(const floatx2*)(seq + ((size_t)(node0 + r1) * T_SEQ + (t + 1)) * S_SEQ + c1r);
            }
        }

        // ---- phase A: layer 0 (kt 0..2: sSeq x IH0, kt 3..6: sH0 x HH0) ----
        #pragma unroll
        for (int g = 0; g < 4; ++g) {
            floatx4 bv = {bias0[g], bias0[g], bias0[g], bias0[g]};
            #pragma unroll
            for (int mt = 0; mt < MT; ++mt) acc[g][mt] = bv;
        }
        #pragma unroll
        for (int kt = 0; kt < 7; ++kt) {
            // DMA next slot (wave-private; vmcnt-ordered, no barrier)
            if (kt < 2)      dma_slot(pIH0, 3, kt + 1, wid, lane, &sW[wb ^ 1][wid][0]);
            else if (kt < 6) dma_slot(pHH0, 4, kt - 2, wid, lane, &sW[wb ^ 1][wid][0]);
            else             dma_slot(pIH1, 4, 0,      wid, lane, &sW[wb ^ 1][wid][0]);
            if (kt < 3)
                mfma_kt(acc, &sW[wb][wid][0], lane, sSeq, SEQ_STRIDE, kt * 32, l15, quad);
            else
                mfma_kt(acc, &sW[wb][wid][0], lane, &sH0[cur][0], H_STRIDE, (kt - 3) * 32, l15, quad);
            wb ^= 1;
        }
        epilogue(acc, c0, &sH0[nxt][0], quad, ch);
        __syncthreads();  // h0(t) visible for layer 1

        // ---- phase B: layer 1 (kt 0..3: sH0[nxt] x IH1, kt 4..7: sH1 x HH1) ----
        #pragma unroll
        for (int g = 0; g < 4; ++g) {
            floatx4 bv = {bias1[g], bias1[g], bias1[g], bias1[g]};
            #pragma unroll
            for (int mt = 0; mt < MT; ++mt) acc[g][mt] = bv;
        }
        #pragma unroll
        for (int kt = 0; kt < 8; ++kt) {
            if (kt < 3)      dma_slot(pIH1, 4, kt + 1, wid, lane, &sW[wb ^ 1][wid][0]);
            else if (kt < 7) dma_slot(pHH1, 4, kt - 3, wid, lane, &sW[wb ^ 1][wid][0]);
            else             dma_slot(pIH0, 3, 0,      wid, lane, &sW[wb ^ 1][wid][0]); // next step
            if (kt < 4)
                mfma_kt(acc, &sW[wb][wid][0], lane, &sH0[nxt][0], H_STRIDE, kt * 32, l15, quad);
            else
                mfma_kt(acc, &sW[wb][wid][0], lane, &sH1[cur][0], H_STRIDE, (kt - 4) * 32, l15, quad);
            wb ^= 1;
        }
        // commit seq(t+1) from prefetch regs (phase-A readers of sSeq are done)
        if (t + 1 < T_SEQ) {
            sSeq[pr * SEQ_STRIDE + pc]     = (_Float16)pf0.x;
            sSeq[pr * SEQ_STRIDE + pc + 1] = (_Float16)pf0.y;
            if (tid < 128) {
                int r1 = (512 + tid) >> 4, c1r = ((512 + tid) & 15) * 2;
                sSeq[r1 * SEQ_STRIDE + c1r]     = (_Float16)pf1.x;
                sSeq[r1 * SEQ_STRIDE + c1r + 1] = (_Float16)pf1.y;
            }
        }
        epilogue(acc, c1, &sH1[nxt][0], quad, ch);
        __syncthreads();  // h1(t) + seq(t+1) visible
    }

    // final h1 lives in buffer (T_SEQ & 1) == 0
    if (tid < M_BLK) {
        const _Float16* h1 = &sH1[0][tid * H_STRIDE];
        float s = fcb[0];
        #pragma unroll 16
        for (int k = 0; k < HID; ++k) s = fmaf((float)h1[k], fcw[k], s);
        out[node0 + tid] = s;
    }
}

// ---------------- launch ----------------
extern "C" void kernel_launch(void* const* d_in, const int* in_sizes, int n_in,
                              void* d_out, int out_size, void* d_ws, size_t ws_size,
                              hipStream_t stream) {
    const float* seq   = (const float*)d_in[0];
    const int*   ei    = (const int*)d_in[1];     // int64 in reference -> int32 on device
    // d_in[2] edge_attr: unused by reference
    const float* nf    = (const float*)d_in[3];
    // d_in[4] node_indices: unused by reference
    const float* gcn_w = (const float*)d_in[5];
    const float* gcn_b = (const float*)d_in[6];
    const float* w_ih0 = (const float*)d_in[7];
    const float* w_hh0 = (const float*)d_in[8];
    const float* b_ih0 = (const float*)d_in[9];
    const float* b_hh0 = (const float*)d_in[10];
    const float* w_ih1 = (const float*)d_in[11];
    const float* w_hh1 = (const float*)d_in[12];
    const float* b_ih1 = (const float*)d_in[13];
    const float* b_hh1 = (const float*)d_in[14];
    const float* fc_w  = (const float*)d_in[15];
    const float* fc_b  = (const float*)d_in[16];
    float* out = (float*)d_out;

    char* ws = (char*)d_ws;
    float* xw   = (float*)(ws);                    // 2,560,000 B
    float* gout = (float*)(ws + 2621440);          // 2,560,000 B
    float* deg  = (float*)(ws + 5242880);          // 40,000 B
    float* dinv = (float*)(ws + 5283840);          // 40,000 B
    float* bsum = (float*)(ws + 5324800);          // 4,096 B
    half8* pW   = (half8*)(ws + 5328896);          // 491,520 B  (16B aligned)

    // GCN (fp32 exact)
    k_gcn_xw     <<<2500,  256, 0, stream>>>(nf, gcn_w, xw);
    k_deg_init   <<<40,    256, 0, stream>>>(deg);
    k_deg_count  <<<625,   256, 0, stream>>>(ei, deg);
    k_dinv       <<<40,    256, 0, stream>>>(deg, dinv);
    k_gcn_self   <<<2500,  256, 0, stream>>>(xw, dinv, gcn_b, gout);
    k_gcn_scatter<<<40000, 256, 0, stream>>>(ei, xw, dinv, gout);

    // weight prep
    k_pack<<<120, 256, 0, stream>>>(w_ih0, w_hh0, w_ih1, w_hh1, pW);
    k_bsum<<<4,   256, 0, stream>>>(b_ih0, b_hh0, b_ih1, b_hh1, bsum);

    // fused 2-layer LSTM + FC
    k_lstm<<<250, 512, 0, stream>>>(seq, gout, pW, bsum, fc_w, fc_b, out);
}

// Round 8
// 1327.798 us; speedup vs baseline: 1.7837x; 1.1477x over previous
//
#include <hip/hip_runtime.h>
#include <hip/hip_bf16.h>

typedef _Float16 half8 __attribute__((ext_vector_type(8)));
typedef float floatx4 __attribute__((ext_vector_type(4)));
typedef float floatx2 __attribute__((ext_vector_type(2)));

#define N_NODES 10000
#define F_NODE  128
#define C_GCN   64
#define N_EDGES 160000
#define T_SEQ   96
#define S_SEQ   32
#define HID     128
#define M_BLK   40          // nodes per block (250 blocks exactly)
#define MT      3           // 3 m-tiles of 16 -> 48 rows (40 real + 8 zero pad)
#define SEQ_STRIDE 104      // 96 + 8 f16 pad (208 B = 13*16)
#define H_STRIDE   136      // 128 + 8 f16 pad (272 B = 17*16)
#define WAVE_STREAM 61440   // bytes of packed weights per wave per step (15 slots x 4 KB)

// ---------------- fast activations: native v_exp_f32 + v_rcp_f32 ----------------
__device__ __forceinline__ float fast_rcp(float x) { return __builtin_amdgcn_rcpf(x); }
__device__ __forceinline__ float sigm_f(float x) {
    return fast_rcp(1.0f + __expf(-x));            // __expf -> v_exp_f32 (native)
}
__device__ __forceinline__ float tanh_f(float x) {
    return 2.0f * fast_rcp(1.0f + __expf(-2.0f * x)) - 1.0f;
}

// ---------------- GCN kernels (all fp32, tiny) ----------------
__global__ void k_gcn_xw(const float* __restrict__ nf, const float* __restrict__ w,
                         float* __restrict__ xw) {
    int tid = blockIdx.x * 256 + threadIdx.x;
    int n = tid >> 6, c = tid & 63;
    if (n >= N_NODES) return;
    float s = 0.f;
    #pragma unroll 8
    for (int k = 0; k < F_NODE; ++k) s = fmaf(nf[n * F_NODE + k], w[k * C_GCN + c], s);
    xw[n * C_GCN + c] = s;
}

__global__ void k_deg_init(float* __restrict__ deg) {
    int i = blockIdx.x * 256 + threadIdx.x;
    if (i < N_NODES) deg[i] = 1.0f;   // self loop
}

__global__ void k_deg_count(const int* __restrict__ ei, float* __restrict__ deg) {
    int e = blockIdx.x * 256 + threadIdx.x;
    if (e < N_EDGES) atomicAdd(&deg[ei[N_EDGES + e]], 1.0f);
}

__global__ void k_dinv(const float* __restrict__ deg, float* __restrict__ dinv) {
    int i = blockIdx.x * 256 + threadIdx.x;
    if (i < N_NODES) dinv[i] = rsqrtf(deg[i]);
}

__global__ void k_gcn_self(const float* __restrict__ xw, const float* __restrict__ dinv,
                           const float* __restrict__ gb, float* __restrict__ gout) {
    int tid = blockIdx.x * 256 + threadIdx.x;
    int n = tid >> 6, c = tid & 63;
    if (n >= N_NODES) return;
    float di = dinv[n];
    gout[tid] = xw[tid] * di * di + gb[c];
}

__global__ void k_gcn_scatter(const int* __restrict__ ei, const float* __restrict__ xw,
                              const float* __restrict__ dinv, float* __restrict__ gout) {
    int e = blockIdx.x * 4 + (threadIdx.x >> 6);
    int c = threadIdx.x & 63;
    if (e >= N_EDGES) return;
    int r  = ei[e];
    int cl = ei[N_EDGES + e];
    float nm = dinv[r] * dinv[cl];
    atomicAdd(&gout[cl * C_GCN + c], xw[r * C_GCN + c] * nm);
}

// ---------------- weight packing: wave-major streaming order ----------------
// pP layout: [wave w:8][slot s:15][gate g:4][lane:64] x half8 (16 B).
// Per wave per step: 15 contiguous 4-KB slots in exact consumption order:
//   s=0..2 IH0(kt=s,K=96), 3..6 HH0(kt=s-3), 7..10 IH1(kt=s-7), 11..14 HH1(kt=s-11)
// lane holds W[g*128 + w*16 + (lane&15)][kt*32 + (lane>>4)*8 + j]
__global__ void k_pack(const float* __restrict__ w_ih0, const float* __restrict__ w_hh0,
                       const float* __restrict__ w_ih1, const float* __restrict__ w_hh1,
                       half8* __restrict__ pP) {
    int tid = blockIdx.x * 256 + threadIdx.x;
    if (tid >= 8 * 15 * 4 * 64) return;
    int lane = tid & 63;
    int g    = (tid >> 6) & 3;
    int s    = (tid >> 8) % 15;
    int w    = tid / 3840;
    const float* src; int kt, K;
    if (s < 3)       { src = w_ih0; kt = s;      K = 96;  }
    else if (s < 7)  { src = w_hh0; kt = s - 3;  K = 128; }
    else if (s < 11) { src = w_ih1; kt = s - 7;  K = 128; }
    else             { src = w_hh1; kt = s - 11; K = 128; }
    int row = g * 128 + w * 16 + (lane & 15);
    int k0  = kt * 32 + (lane >> 4) * 8;
    half8 v;
    #pragma unroll
    for (int j = 0; j < 8; ++j) v[j] = (_Float16)src[row * K + k0 + j];
    pP[tid] = v;
}

__global__ void k_bsum(const float* __restrict__ bi0, const float* __restrict__ bh0,
                       const float* __restrict__ bi1, const float* __restrict__ bh1,
                       float* __restrict__ bs) {
    int i = blockIdx.x * 256 + threadIdx.x;
    if (i < 512)       bs[i] = bi0[i] + bh0[i];
    else if (i < 1024) bs[i] = bi1[i - 512] + bh1[i - 512];
}

// ---------------- fused 2-layer LSTM + FC ----------------
// async 16B-per-lane DMA: global -> LDS. Global address is PER-LANE (src + lane*16);
// LDS dest is wave-uniform base + lane*16 (hardware rule).
__device__ __forceinline__ void async_copy16(const void* g, void* l) {
    __builtin_amdgcn_global_load_lds(
        (const __attribute__((address_space(1))) unsigned int*)g,
        (__attribute__((address_space(3))) unsigned int*)l, 16, 0, 0);
}

// DMA one 4-KB slot (4 gate-frags) from this wave's contiguous stream into LDS
__device__ __forceinline__ void dma_slot(const char* __restrict__ src, int lane, _Float16* slot) {
    #pragma unroll
    for (int g = 0; g < 4; ++g)
        async_copy16((const void*)(src + g * 1024 + lane * 16), (void*)(slot + g * 512));
}

// consume one k-tile slot: 4 B ds_reads + 3 A ds_reads + 12 MFMAs
__device__ __forceinline__ void mfma_kt(floatx4 acc[4][MT], const _Float16* slot, int lane,
                                        const _Float16* A, int strideA, int koff,
                                        int l15, int quad) {
    half8 bg[4], a[MT];
    #pragma unroll
    for (int g = 0; g < 4; ++g) bg[g] = *(const half8*)(slot + g * 512 + lane * 8);
    #pragma unroll
    for (int mt = 0; mt < MT; ++mt)
        a[mt] = *(const half8*)(A + (mt * 16 + l15) * strideA + koff + quad * 8);
    #pragma unroll
    for (int g = 0; g < 4; ++g)
        #pragma unroll
        for (int mt = 0; mt < MT; ++mt)
            acc[g][mt] = __builtin_amdgcn_mfma_f32_16x16x32_f16(a[mt], bg[g], acc[g][mt], 0, 0, 0);
}

__device__ __forceinline__ void epilogue(floatx4 acc[4][MT],
                                         float c[MT][4], _Float16* Hnext,
                                         int quad, int ch) {
    #pragma unroll
    for (int mt = 0; mt < MT; ++mt) {
        #pragma unroll
        for (int r = 0; r < 4; ++r) {
            float gi = acc[0][mt][r];
            float gf = acc[1][mt][r];
            float gg = acc[2][mt][r];
            float go = acc[3][mt][r];
            float cn = sigm_f(gf) * c[mt][r] + sigm_f(gi) * tanh_f(gg);
            c[mt][r] = cn;
            float h = sigm_f(go) * tanh_f(cn);
            Hnext[(mt * 16 + quad * 4 + r) * H_STRIDE + ch] = (_Float16)h;
        }
    }
}

__global__ __launch_bounds__(512, 2) void k_lstm(
    const float* __restrict__ seq, const float* __restrict__ gcn,
    const char* __restrict__ pW, const float* __restrict__ bsum,
    const float* __restrict__ fcw, const float* __restrict__ fcb,
    float* __restrict__ out) {

    __shared__ __align__(16) _Float16 sSeq[48 * SEQ_STRIDE];          //  9,984 B
    __shared__ __align__(16) _Float16 sH0[2][48 * H_STRIDE];          // 26,112 B
    __shared__ __align__(16) _Float16 sH1[2][48 * H_STRIDE];          // 26,112 B
    __shared__ __align__(16) _Float16 sW[2][8][2048];                 // 65,536 B (2-slot ring)

    const int tid  = threadIdx.x;
    const int wid  = tid >> 6;
    const int lane = tid & 63;
    const int l15  = lane & 15;
    const int quad = lane >> 4;
    const int node0 = blockIdx.x * M_BLK;
    const int ch = wid * 16 + l15;

    const char* pWw = pW + wid * WAVE_STREAM;   // this wave's contiguous weight stream

    // prologue DMA: slot 0 into ring 0 (in flight during setup)
    dma_slot(pWw, lane, &sW[0][wid][0]);

    // zero LDS A-buffers (pad rows 40..47 stay zero forever)
    for (int i = tid; i < 48 * SEQ_STRIDE; i += 512) sSeq[i] = (_Float16)0.f;
    for (int i = tid; i < 48 * H_STRIDE; i += 512) {
        sH0[0][i] = (_Float16)0.f; sH0[1][i] = (_Float16)0.f;
        sH1[0][i] = (_Float16)0.f; sH1[1][i] = (_Float16)0.f;
    }

    float bias0[4], bias1[4];
    #pragma unroll
    for (int g = 0; g < 4; ++g) {
        bias0[g] = bsum[g * 128 + ch];
        bias1[g] = bsum[512 + g * 128 + ch];
    }

    float c0[MT][4] = {{0}}, c1[MT][4] = {{0}};

    __syncthreads();

    // stage constant gcn columns (32..95) and seq t=0 (cols 0..31)
    for (int i = tid; i < M_BLK * (C_GCN / 2); i += 512) {
        int r = i >> 5, cp = (i & 31) * 2;
        floatx2 v = *(const floatx2*)(gcn + (size_t)(node0 + r) * C_GCN + cp);
        sSeq[r * SEQ_STRIDE + S_SEQ + cp]     = (_Float16)v.x;
        sSeq[r * SEQ_STRIDE + S_SEQ + cp + 1] = (_Float16)v.y;
    }
    {
        int r = tid >> 4, cp = (tid & 15) * 2;
        if (tid < M_BLK * 16) {
            floatx2 v = *(const floatx2*)(seq + ((size_t)(node0 + r) * T_SEQ) * S_SEQ + cp);
            sSeq[r * SEQ_STRIDE + cp]     = (_Float16)v.x;
            sSeq[r * SEQ_STRIDE + cp + 1] = (_Float16)v.y;
        }
    }
    __syncthreads();

    floatx4 acc[4][MT];
    const int pr = tid >> 4, pc = (tid & 15) * 2;   // seq prefetch slot
    int wb = 0;                                     // wave-private ring parity

    for (int t = 0; t < T_SEQ; ++t) {
        const int cur = t & 1, nxt = cur ^ 1;

        // register prefetch of seq(t+1): in flight through phase A
        floatx2 pf0 = {0.f, 0.f}, pf1 = {0.f, 0.f};
        if (t + 1 < T_SEQ) {
            pf0 = *(const floatx2*)(seq + ((size_t)(node0 + pr) * T_SEQ + (t + 1)) * S_SEQ + pc);
            if (tid < 128) {
                int r1 = (512 + tid) >> 4, c1r = ((512 + tid) & 15) * 2;
                pf1 = *(const floatx2*)(seq + ((size_t)(node0 + r1) * T_SEQ + (t + 1)) * S_SEQ + c1r);
            }
        }

        // ---- phase A: slots 0..6 (0..2: sSeq x IH0, 3..6: sH0 x HH0) ----
        #pragma unroll
        for (int g = 0; g < 4; ++g) {
            floatx4 bv = {bias0[g], bias0[g], bias0[g], bias0[g]};
            #pragma unroll
            for (int mt = 0; mt < MT; ++mt) acc[g][mt] = bv;
        }
        #pragma unroll
        for (int s = 0; s < 7; ++s) {
            dma_slot(pWw + (s + 1) * 4096, lane, &sW[wb ^ 1][wid][0]);   // next slot
            if (s < 3)
                mfma_kt(acc, &sW[wb][wid][0], lane, sSeq, SEQ_STRIDE, s * 32, l15, quad);
            else
                mfma_kt(acc, &sW[wb][wid][0], lane, &sH0[cur][0], H_STRIDE, (s - 3) * 32, l15, quad);
            wb ^= 1;
        }
        epilogue(acc, c0, &sH0[nxt][0], quad, ch);
        __syncthreads();  // h0(t) visible for layer 1

        // ---- phase B: slots 7..14 (7..10: sH0[nxt] x IH1, 11..14: sH1 x HH1) ----
        #pragma unroll
        for (int g = 0; g < 4; ++g) {
            floatx4 bv = {bias1[g], bias1[g], bias1[g], bias1[g]};
            #pragma unroll
            for (int mt = 0; mt < MT; ++mt) acc[g][mt] = bv;
        }
        #pragma unroll
        for (int s = 7; s < 15; ++s) {
            dma_slot(pWw + ((s + 1) % 15) * 4096, lane, &sW[wb ^ 1][wid][0]); // wraps to slot 0
            if (s < 11)
                mfma_kt(acc, &sW[wb][wid][0], lane, &sH0[nxt][0], H_STRIDE, (s - 7) * 32, l15, quad);
            else
                mfma_kt(acc, &sW[wb][wid][0], lane, &sH1[cur][0], H_STRIDE, (s - 11) * 32, l15, quad);
            wb ^= 1;
        }
        // commit seq(t+1) from prefetch regs (phase-A readers of sSeq are done)
        if (t + 1 < T_SEQ) {
            sSeq[pr * SEQ_STRIDE + pc]     = (_Float16)pf0.x;
            sSeq[pr * SEQ_STRIDE + pc + 1] = (_Float16)pf0.y;
            if (tid < 128) {
                int r1 = (512 + tid) >> 4, c1r = ((512 + tid) & 15) * 2;
                sSeq[r1 * SEQ_STRIDE + c1r]     = (_Float16)pf1.x;
                sSeq[r1 * SEQ_STRIDE + c1r + 1] = (_Float16)pf1.y;
            }
        }
        epilogue(acc, c1, &sH1[nxt][0], quad, ch);
        __syncthreads();  // h1(t) + seq(t+1) visible
    }

    // final h1 lives in buffer (T_SEQ & 1) == 0
    if (tid < M_BLK) {
        const _Float16* h1 = &sH1[0][tid * H_STRIDE];
        float s = fcb[0];
        #pragma unroll 16
        for (int k = 0; k < HID; ++k) s = fmaf((float)h1[k], fcw[k], s);
        out[node0 + tid] = s;
    }
}

// ---------------- launch ----------------
extern "C" void kernel_launch(void* const* d_in, const int* in_sizes, int n_in,
                              void* d_out, int out_size, void* d_ws, size_t ws_size,
                              hipStream_t stream) {
    const float* seq   = (const float*)d_in[0];
    const int*   ei    = (const int*)d_in[1];     // int64 in reference -> int32 on device
    // d_in[2] edge_attr: unused by reference
    const float* nf    = (const float*)d_in[3];
    // d_in[4] node_indices: unused by reference
    const float* gcn_w = (const float*)d_in[5];
    const float* gcn_b = (const float*)d_in[6];
    const float* w_ih0 = (const float*)d_in[7];
    const float* w_hh0 = (const float*)d_in[8];
    const float* b_ih0 = (const float*)d_in[9];
    const float* b_hh0 = (const float*)d_in[10];
    const float* w_ih1 = (const float*)d_in[11];
    const float* w_hh1 = (const float*)d_in[12];
    const float* b_ih1 = (const float*)d_in[13];
    const float* b_hh1 = (const float*)d_in[14];
    const float* fc_w  = (const float*)d_in[15];
    const float* fc_b  = (const float*)d_in[16];
    float* out = (float*)d_out;

    char* ws = (char*)d_ws;
    float* xw   = (float*)(ws);                    // 2,560,000 B
    float* gout = (float*)(ws + 2621440);          // 2,560,000 B
    float* deg  = (float*)(ws + 5242880);          // 40,000 B
    float* dinv = (float*)(ws + 5283840);          // 40,000 B
    float* bsum = (float*)(ws + 5324800);          // 4,096 B
    char*  pP   = (char*)(ws + 5328896);           // 491,520 B (16B aligned)

    // GCN (fp32 exact)
    k_gcn_xw     <<<2500,  256, 0, stream>>>(nf, gcn_w, xw);
    k_deg_init   <<<40,    256, 0, stream>>>(deg);
    k_deg_count  <<<625,   256, 0, stream>>>(ei, deg);
    k_dinv       <<<40,    256, 0, stream>>>(deg, dinv);
    k_gcn_self   <<<2500,  256, 0, stream>>>(xw, dinv, gcn_b, gout);
    k_gcn_scatter<<<40000, 256, 0, stream>>>(ei, xw, dinv, gout);

    // weight prep (wave-major streaming layout)
    k_pack<<<120, 256, 0, stream>>>(w_ih0, w_hh0, w_ih1, w_hh1, (half8*)pP);
    k_bsum<<<4,   256, 0, stream>>>(b_ih0, b_hh0, b_ih1, b_hh1, bsum);

    // fused 2-layer LSTM + FC
    k_lstm<<<250, 512, 0, stream>>>(seq, gout, pP, bsum, fc_w, fc_b, out);
}